// Round 17
// baseline (10765.384 us; speedup 1.0000x reference)
//
#include <hip/hip_runtime.h>
#include <cstdint>

#define NPIX 16384
#define KNN 8
#define PW 130                 // padded width/height
#define NPPAD (PW * PW)        // padded positions: 16900
#define NPH 8                  // phases (4 channels each)

typedef float f32x4 __attribute__((ext_vector_type(4)));
typedef __attribute__((address_space(3))) uint32_t lds_u32_t;
typedef const __attribute__((address_space(1))) uint32_t glob_u32_t;

// ---------------- Threefry-2x32 (exact JAX semantics: 20 rounds) ----------------
__host__ __device__ __forceinline__ void tf2x32(uint32_t k0, uint32_t k1,
                                                uint32_t x0, uint32_t x1,
                                                uint32_t& o0, uint32_t& o1) {
  uint32_t ks2 = k0 ^ k1 ^ 0x1BD11BDAu;
  x0 += k0; x1 += k1;
#define TFR(r) { x0 += x1; x1 = (x1 << r) | (x1 >> (32 - r)); x1 ^= x0; }
  TFR(13) TFR(15) TFR(26) TFR(6)  x0 += k1;  x1 += ks2 + 1u;
  TFR(17) TFR(29) TFR(16) TFR(24) x0 += ks2; x1 += k0 + 2u;
  TFR(13) TFR(15) TFR(26) TFR(6)  x0 += k0;  x1 += k1 + 3u;
  TFR(17) TFR(29) TFR(16) TFR(24) x0 += k1;  x1 += ks2 + 4u;
  TFR(13) TFR(15) TFR(26) TFR(6)  x0 += ks2; x1 += k0 + 5u;
#undef TFR
  o0 = x0; o1 = x1;
}

// partitionable-threefry random_bits (32-bit): element j -> w0^w1 of TF(key,(0,j))
__device__ __forceinline__ uint32_t rbits32(uint32_t ka, uint32_t kb, uint32_t j) {
  uint32_t o0, o1;
  tf2x32(ka, kb, 0u, j, o0, o1);
  return o0 ^ o1;
}

// randint element draw; K = (k1a,k1b,k2a,k2b) = foldlike-split of randint key
__device__ __forceinline__ int rnd_int(uint4 K, uint32_t j, uint32_t span,
                                       uint32_t mult, int minv) {
  uint32_t hi = rbits32(K.x, K.y, j);
  uint32_t lo = rbits32(K.z, K.w, j);
  uint32_t off = ((hi % span) * mult + (lo % span)) % span;
  return minv + (int)off;
}

// ---------------- per-lane patch SSD cost (init only), [8][130][130][4] ---------
// Bit-exact channel-ascending (ch = ph*4+j), positions-inner accumulation.
__device__ __forceinline__ float cost_eval_pl(const float* __restrict__ apt,
                                              const float* __restrict__ bpt,
                                              int py0, int px0, int sy, int sx) {
  float acc = 0.f;
#pragma unroll
  for (int ph = 0; ph < NPH; ++ph) {
    const float* ab = apt + ((size_t)ph * NPPAD + (size_t)(py0 * PW + px0)) * 4;
    const float* bb = bpt + ((size_t)ph * NPPAD + (size_t)(sy * PW + sx)) * 4;
    f32x4 av[9], bv[9];
#pragma unroll
    for (int p = 0; p < 9; ++p) {
      int dy = p / 3, dx = p - dy * 3;
      av[p] = *(const f32x4*)(ab + (dy * PW + dx) * 4);
      bv[p] = *(const f32x4*)(bb + (dy * PW + dx) * 4);
    }
#pragma unroll
    for (int j = 0; j < 4; ++j) {
#pragma unroll
      for (int p = 0; p < 9; ++p) {
        float d = __fsub_rn(av[p][j], bv[p][j]);
        acc = __fadd_rn(acc, __fmul_rn(d, d));
      }
    }
  }
  return acc;
}

// ---------------- pad + transpose a,b to [8][130][130][4] -----------------------
__global__ __launch_bounds__(256) void pad_kernel(
    const float* __restrict__ a, const float* __restrict__ b,
    float* __restrict__ apt, float* __restrict__ bpt) {
  int t = (int)(blockIdx.x * blockDim.x + threadIdx.x);
  if (t >= 32 * NPPAD) return;
  int lo = t & 3;
  int rest = t >> 2;
  int pos = rest % NPPAD;
  int ph = rest / NPPAD;
  int c = ph * 4 + lo;
  int py = pos / PW, px = pos % PW;
  int y = py - 1; y = y < 0 ? 0 : (y > 127 ? 127 : y);
  int x = px - 1; x = x < 0 ? 0 : (x > 127 ? 127 : x);
  int src = (c << 14) + (y << 7) + x;
  apt[t] = a[src];
  bpt[t] = b[src];
}

// ---------------- init: random shifts + their costs (full-wave) -----------------
__global__ __launch_bounds__(256) void init_kernel(
    const float* __restrict__ apt, const float* __restrict__ bpt,
    uint32_t* __restrict__ npack, float* __restrict__ ncost, uint4 IK) {
  int t = (int)(blockIdx.x * blockDim.x + threadIdx.x);  // 8*16384
  int pix = t & (NPIX - 1);
  int s = t >> 14;
  int py0 = pix >> 7, px0 = pix & 127;
  uint32_t j0 = (uint32_t)(s * 2) * 16384u + (uint32_t)pix;
  int sy = rnd_int(IK, j0, 128u, 0u, 0);
  int sx = rnd_int(IK, j0 + 16384u, 128u, 0u, 0);
  float cst = cost_eval_pl(apt, bpt, py0, px0, sy, sx);
  npack[t] = (uint32_t)((sy << 7) | sx);
  ncost[t] = cst;
}

// ---------------- one PatchMatch iteration --------------------------------------
// R14 structure (single 9216B gl_lds buffer, vmcnt(0)/lgkmcnt(0) pipeline) plus
// DUP-MASKED STAGING: candidates bit-equal to a carried shift have bit-identical
// cost (R3/R4-verified); their staging loads are exec-masked out -> fewer TA
// line-visits and less L2 traffic (the measured binder). Dup lanes' LDS slots
// stay stale; their acc is discarded by the final select.
__global__ __launch_bounds__(64, 4) void step_kernel(
    const float* __restrict__ apt, const float* __restrict__ bpt,
    const uint32_t* __restrict__ ppack, const float* __restrict__ pcost,
    uint32_t* __restrict__ npack, float* __restrict__ ncost,
    uint4 K0, uint4 K1, uint4 K2, uint4 K3) {
  __shared__ f32x4 ldsb[576];          // 9216 B single buffer for b
  __shared__ f32x4 ldsa[72];           // 1152 B a-patch (8 phases x 9 positions)
  int bidx = (int)blockIdx.x;
  int pix = ((bidx & 7) << 11) | (bidx >> 3);   // XCD-contiguous remap (16384 = 8*2048)
  int lane = (int)threadIdx.x;
  int py0 = pix >> 7, px0 = pix & 127;
  int g = lane >> 3, s = lane & 7;

  uint32_t old_pack = 0u; float old_cost_f = 0.f;
  if (lane < 8) {
    old_pack = ppack[lane * NPIX + pix];
    old_cost_f = pcost[lane * NPIX + pix];
  }

  // candidate generation; order matches all_s = [old8, left8, right8, up8, down8, r0..r3]
  int sy, sx;
  if (g < 4) {
    int nh = py0, nw = px0, dsy = 0, dsx = 0;
    if (g == 0)      { nw = (px0 + 127) & 127; dsx = 1;  }
    else if (g == 1) { nw = (px0 + 1) & 127;   dsx = -1; }
    else if (g == 2) { nh = (py0 + 127) & 127; dsy = 1;  }
    else             { nh = (py0 + 1) & 127;   dsy = -1; }
    uint32_t p = ppack[s * NPIX + (nh << 7) + nw];
    sy = (int)(p >> 7) + dsy;
    sx = (int)(p & 127u) + dsx;
  } else {
    uint32_t p = ppack[s * NPIX + pix];
    uint4 Ki      = (g == 4) ? K0   : (g == 5) ? K1  : (g == 6) ? K2 : K3;
    uint32_t span = (g == 4) ? 129u : (g == 5) ? 33u : (g == 6) ? 9u : 3u;
    uint32_t mult = (g == 4) ? 16u  : (g == 5) ? 4u  : (g == 6) ? 4u : 1u;
    int minv      = (g == 4) ? -64  : (g == 5) ? -16 : (g == 6) ? -4 : -1;
    uint32_t j0 = (uint32_t)(s * 2) * 16384u + (uint32_t)pix;
    sy = (int)(p >> 7)   + rnd_int(Ki, j0, span, mult, minv);
    sx = (int)(p & 127u) + rnd_int(Ki, j0 + 16384u, span, mult, minv);
  }
  sy = sy < 0 ? 0 : (sy > 127 ? 127 : sy);
  sx = sx < 0 ? 0 : (sx > 127 ? 127 : sx);
  uint32_t cnd_pack = (uint32_t)((sy << 7) | sx);

  // ---- dup-vs-old detection (bit-safe: equal shift => bit-identical cost) -----
  bool dupOld = false; float dup_cost = 0.f;
#pragma unroll
  for (int i = 0; i < 8; ++i) {
    uint32_t op = (uint32_t)__shfl((int)old_pack, i);
    float oc = __shfl(old_cost_f, i);
    bool m = (op == cnd_pack);
    dupOld = dupOld || m;
    dup_cost = m ? oc : dup_cost;
  }
  unsigned long long dup_mask = __ballot(dupOld);   // bit c = candidate c is dup

  // ---- staging descriptors (phase-independent): lane stages 16B quad
  // f = i*64+lane of flat (candidate c = f/9, position p = f%9); computed once.
  int base_[9];
  int cidx_[9];
#pragma unroll
  for (int i = 0; i < 9; ++i) {
    int f = i * 64 + lane;
    int c = f / 9, p = f - c * 9;
    int dy = p / 3, dx = p - dy * 3;
    uint32_t pk = (uint32_t)__shfl((int)cnd_pack, c);
    int py = (int)(pk >> 7) + dy;
    int px = (int)(pk & 127u) + dx;
    base_[i] = (py * PW + px) * 4;
    cidx_[i] = c;
  }

  // ---- prologue: a-patch (72 quads) + b phase 0 via global_load_lds -----------
  {
    int q = lane;
    int ph = q / 9, pos = q - ph * 9;
    int dy = pos / 3, dx = pos - dy * 3;
    const float* gp = apt + (size_t)ph * (NPPAD * 4)
                     + (size_t)((py0 + dy) * PW + (px0 + dx)) * 4;
    __builtin_amdgcn_global_load_lds((glob_u32_t*)gp, (lds_u32_t*)&ldsa[0], 16, 0, 0);
  }
  if (lane < 8) {
    int q = 64 + lane;
    int ph = q / 9, pos = q - ph * 9;
    int dy = pos / 3, dx = pos - dy * 3;
    const float* gp = apt + (size_t)ph * (NPPAD * 4)
                     + (size_t)((py0 + dy) * PW + (px0 + dx)) * 4;
    __builtin_amdgcn_global_load_lds((glob_u32_t*)gp, (lds_u32_t*)&ldsa[64], 16, 0, 0);
  }

#define GLB(PH)                                                             \
  _Pragma("unroll")                                                         \
  for (int i = 0; i < 9; ++i) {                                             \
    if (!((dup_mask >> cidx_[i]) & 1ull)) {                                 \
      __builtin_amdgcn_global_load_lds(                                     \
          (glob_u32_t*)(bpt + (size_t)(PH) * (NPPAD * 4) + base_[i]),       \
          (lds_u32_t*)&ldsb[i * 64], 16, 0, 0);                             \
    }                                                                       \
  }

  GLB(0)

  // ---- 8 phases; accumulation ch = ph*4+j ascending, positions inner ->
  // bit-identical to reference (dup lanes' acc is garbage, discarded below).
  float acc = 0.f;

#define PHASE(PH, DOGL)                                                     \
  asm volatile("s_waitcnt vmcnt(0)" ::: "memory");                          \
  {                                                                         \
    f32x4 av[9], bv[9];                                                     \
    _Pragma("unroll")                                                       \
    for (int p = 0; p < 9; ++p) {                                           \
      bv[p] = ldsb[lane * 9 + p];                                           \
      av[p] = ldsa[(PH) * 9 + p];                                           \
    }                                                                       \
    asm volatile("s_waitcnt lgkmcnt(0)" ::: "memory");                      \
    DOGL                                                                    \
    _Pragma("unroll")                                                       \
    for (int j = 0; j < 4; ++j) {                                           \
      _Pragma("unroll")                                                     \
      for (int p = 0; p < 9; ++p) {                                         \
        float d = __fsub_rn(av[p][j], bv[p][j]);                            \
        acc = __fadd_rn(acc, __fmul_rn(d, d));                              \
      }                                                                     \
    }                                                                       \
  }

  PHASE(0, GLB(1))
  PHASE(1, GLB(2))
  PHASE(2, GLB(3))
  PHASE(3, GLB(4))
  PHASE(4, GLB(5))
  PHASE(5, GLB(6))
  PHASE(6, GLB(7))
  PHASE(7, )
#undef PHASE
#undef GLB

  float cnd_cost = dupOld ? dup_cost : acc;

  // stable top-8 (ascending cost, ties -> lower candidate idx), matching
  // lax.top_k. SELECT and EXTRACT fused per round to minimize live registers.
  unsigned long long new_key =
      ((unsigned long long)__float_as_uint(cnd_cost) << 32) | (unsigned)(8 + lane);
  unsigned long long old_key = (lane < 8)
      ? (((unsigned long long)__float_as_uint(old_cost_f) << 32) | (unsigned)lane)
      : ~0ull;
  bool new_used = false, old_used = (lane >= 8);

  uint32_t out_pack = 0u; float out_cost = 0.f;
#define TOPK_ROUND(R)                                                      \
  {                                                                        \
    unsigned long long kmin = new_used ? ~0ull : new_key;                  \
    if (!old_used && old_key < kmin) kmin = old_key;                       \
    _Pragma("unroll")                                                      \
    for (int off = 32; off; off >>= 1) {                                   \
      unsigned long long o = __shfl_xor(kmin, off);                        \
      if (o < kmin) kmin = o;                                              \
    }                                                                      \
    if (!new_used && new_key == kmin) new_used = true;                     \
    else if (!old_used && old_key == kmin) old_used = true;                \
    uint32_t idx = (uint32_t)kmin;                                         \
    float cst = __uint_as_float((uint32_t)(kmin >> 32));                   \
    int srcOld = (idx < 8u) ? (int)idx : 0;                                \
    int srcNew = (idx >= 8u) ? (int)(idx - 8u) : 0;                        \
    uint32_t po = __shfl(old_pack, srcOld);                                \
    uint32_t pn = __shfl(cnd_pack, srcNew);                                \
    uint32_t pk = (idx < 8u) ? po : pn;                                    \
    if (lane == R) { out_pack = pk; out_cost = cst; }                      \
  }
  TOPK_ROUND(0) TOPK_ROUND(1) TOPK_ROUND(2) TOPK_ROUND(3)
  TOPK_ROUND(4) TOPK_ROUND(5) TOPK_ROUND(6) TOPK_ROUND(7)
#undef TOPK_ROUND

  if (lane < 8) {
    npack[lane * NPIX + pix] = out_pack;
    ncost[lane * NPIX + pix] = out_cost;
  }
}

// ---------------- softmax weights over 8 costs ----------------------------------
__global__ __launch_bounds__(256) void weights_kernel(
    const float* __restrict__ cost0, float* __restrict__ wbuf) {
  int pix = (int)(blockIdx.x * blockDim.x + threadIdx.x);
  if (pix >= NPIX) return;
  float c[KNN];
  float m = 3.4e38f;
#pragma unroll
  for (int s = 0; s < KNN; ++s) { c[s] = cost0[s * NPIX + pix]; m = fminf(m, c[s]); }
  float e[KNN]; float sum = 0.f;
#pragma unroll
  for (int s = 0; s < KNN; ++s) { e[s] = expf(m - c[s]); sum += e[s]; }
  float inv = 1.f / sum;
#pragma unroll
  for (int s = 0; s < KNN; ++s) wbuf[s * NPIX + pix] = e[s] * inv;
}

// ---------------- weighted gather of v ------------------------------------------
__global__ __launch_bounds__(256) void out_kernel(
    const float* __restrict__ v, const uint32_t* __restrict__ pack0,
    const float* __restrict__ wbuf, float* __restrict__ out) {
  int t = (int)(blockIdx.x * blockDim.x + threadIdx.x);  // 4*64*128*128 threads
  int pix = t & (NPIX - 1);
  int ch = t >> 14;  // n*64 + c2
  const float* vc = v + ((size_t)ch << 14);
  float acc = 0.f;
#pragma unroll
  for (int s = 0; s < KNN; ++s) {
    uint32_t p = pack0[s * NPIX + pix];   // p == sy*128+sx
    float wgt = wbuf[s * NPIX + pix];
    acc = fmaf(wgt, vc[p], acc);
  }
  out[t] = acc;
}

// ---------------- host helpers ---------------------------------------------------
// foldlike split (jax_threefry_partitionable=True): key_i = TF(key, (0, i))
static void h_split_fl(uint32_t ka, uint32_t kb, uint32_t o[4]) {
  tf2x32(ka, kb, 0u, 0u, o[0], o[1]);  // keys[0]
  tf2x32(ka, kb, 0u, 1u, o[2], o[3]);  // keys[1]
}

extern "C" void kernel_launch(void* const* d_in, const int* in_sizes, int n_in,
                              void* d_out, int out_size, void* d_ws, size_t ws_size,
                              hipStream_t stream) {
  const float* q = (const float*)d_in[0];  // (1,32,128,128)
  const float* k = (const float*)d_in[1];  // (1,32,128,128)
  const float* v = (const float*)d_in[2];  // (4,64,128,128)
  float* out = (float*)d_out;

  uint32_t* ws = (uint32_t*)d_ws;
  uint32_t* pk[2] = { ws, ws + (size_t)KNN * NPIX };
  float* ct[2] = { (float*)(ws + (size_t)2 * KNN * NPIX),
                   (float*)(ws + (size_t)3 * KNN * NPIX) };
  float* wbuf = (float*)(ws + (size_t)4 * KNN * NPIX);
  float* apt  = (float*)(ws + (size_t)5 * KNN * NPIX);
  float* bpt  = apt + (size_t)32 * NPPAD;

  // key chain on host (pure arithmetic; graph-capture safe, deterministic)
  uint32_t sp[4];
  h_split_fl(0u, 42u, sp);                      // split(key(42)) [foldlike]
  uint32_t k0a = sp[0], k0b = sp[1];            // k0  (initial randint key)
  uint32_t kMa = sp[2], kMb = sp[3];            // key (closed over by scan body)

  pad_kernel<<<(32 * NPPAD + 255) / 256, 256, 0, stream>>>(q, k, apt, bpt);

  uint32_t ik[4];
  h_split_fl(k0a, k0b, ik);                     // randint's internal split of k0
  init_kernel<<<(KNN * NPIX) / 256, 256, 0, stream>>>(apt, bpt, pk[0], ct[0],
                                        make_uint4(ik[0], ik[1], ik[2], ik[3]));

  for (int it = 0; it < 10; ++it) {
    uint32_t ka, kb;
    tf2x32(kMa, kMb, 0u, (uint32_t)it, ka, kb); // kk = fold_in(key, it)
    uint4 K[4];
    for (int i = 0; i < 4; ++i) {
      uint32_t ia, ib;
      tf2x32(ka, kb, 0u, (uint32_t)i, ia, ib);  // ki = fold_in(kk, i)
      uint32_t o[4];
      h_split_fl(ia, ib, o);                    // randint's internal split of ki
      K[i] = make_uint4(o[0], o[1], o[2], o[3]);
    }
    step_kernel<<<NPIX, 64, 0, stream>>>(apt, bpt, pk[it & 1], ct[it & 1],
                                         pk[(it + 1) & 1], ct[(it + 1) & 1],
                                         K[0], K[1], K[2], K[3]);
  }

  weights_kernel<<<NPIX / 256, 256, 0, stream>>>(ct[0], wbuf);
  out_kernel<<<(4 * 64 * NPIX) / 256, 256, 0, stream>>>(v, pk[0], wbuf, out);
}

// Round 18
// 905.365 us; speedup vs baseline: 11.8907x; 11.8907x over previous
//
#include <hip/hip_runtime.h>
#include <cstdint>

#define NPIX 16384
#define KNN 8
#define PW 130                 // padded width/height
#define NPPAD (PW * PW)        // padded positions: 16900
#define NPH 8                  // phases (4 channels each)

typedef float f32x4 __attribute__((ext_vector_type(4)));
typedef __attribute__((address_space(3))) uint32_t lds_u32_t;
typedef const __attribute__((address_space(1))) uint32_t glob_u32_t;

// ---------------- Threefry-2x32 (exact JAX semantics: 20 rounds) ----------------
__host__ __device__ __forceinline__ void tf2x32(uint32_t k0, uint32_t k1,
                                                uint32_t x0, uint32_t x1,
                                                uint32_t& o0, uint32_t& o1) {
  uint32_t ks2 = k0 ^ k1 ^ 0x1BD11BDAu;
  x0 += k0; x1 += k1;
#define TFR(r) { x0 += x1; x1 = (x1 << r) | (x1 >> (32 - r)); x1 ^= x0; }
  TFR(13) TFR(15) TFR(26) TFR(6)  x0 += k1;  x1 += ks2 + 1u;
  TFR(17) TFR(29) TFR(16) TFR(24) x0 += ks2; x1 += k0 + 2u;
  TFR(13) TFR(15) TFR(26) TFR(6)  x0 += k0;  x1 += k1 + 3u;
  TFR(17) TFR(29) TFR(16) TFR(24) x0 += k1;  x1 += ks2 + 4u;
  TFR(13) TFR(15) TFR(26) TFR(6)  x0 += ks2; x1 += k0 + 5u;
#undef TFR
  o0 = x0; o1 = x1;
}

// partitionable-threefry random_bits (32-bit): element j -> w0^w1 of TF(key,(0,j))
__device__ __forceinline__ uint32_t rbits32(uint32_t ka, uint32_t kb, uint32_t j) {
  uint32_t o0, o1;
  tf2x32(ka, kb, 0u, j, o0, o1);
  return o0 ^ o1;
}

// randint element draw; K = (k1a,k1b,k2a,k2b) = foldlike-split of randint key
__device__ __forceinline__ int rnd_int(uint4 K, uint32_t j, uint32_t span,
                                       uint32_t mult, int minv) {
  uint32_t hi = rbits32(K.x, K.y, j);
  uint32_t lo = rbits32(K.z, K.w, j);
  uint32_t off = ((hi % span) * mult + (lo % span)) % span;
  return minv + (int)off;
}

// ---------------- per-lane patch SSD cost (init only), [8][130][130][4] ---------
// Bit-exact channel-ascending (ch = ph*4+j), positions-inner accumulation.
__device__ __forceinline__ float cost_eval_pl(const float* __restrict__ apt,
                                              const float* __restrict__ bpt,
                                              int py0, int px0, int sy, int sx) {
  float acc = 0.f;
#pragma unroll
  for (int ph = 0; ph < NPH; ++ph) {
    const float* ab = apt + ((size_t)ph * NPPAD + (size_t)(py0 * PW + px0)) * 4;
    const float* bb = bpt + ((size_t)ph * NPPAD + (size_t)(sy * PW + sx)) * 4;
    f32x4 av[9], bv[9];
#pragma unroll
    for (int p = 0; p < 9; ++p) {
      int dy = p / 3, dx = p - dy * 3;
      av[p] = *(const f32x4*)(ab + (dy * PW + dx) * 4);
      bv[p] = *(const f32x4*)(bb + (dy * PW + dx) * 4);
    }
#pragma unroll
    for (int j = 0; j < 4; ++j) {
#pragma unroll
      for (int p = 0; p < 9; ++p) {
        float d = __fsub_rn(av[p][j], bv[p][j]);
        acc = __fadd_rn(acc, __fmul_rn(d, d));
      }
    }
  }
  return acc;
}

// ---------------- pad + transpose a,b to [8][130][130][4] -----------------------
__global__ __launch_bounds__(256) void pad_kernel(
    const float* __restrict__ a, const float* __restrict__ b,
    float* __restrict__ apt, float* __restrict__ bpt) {
  int t = (int)(blockIdx.x * blockDim.x + threadIdx.x);
  if (t >= 32 * NPPAD) return;
  int lo = t & 3;
  int rest = t >> 2;
  int pos = rest % NPPAD;
  int ph = rest / NPPAD;
  int c = ph * 4 + lo;
  int py = pos / PW, px = pos % PW;
  int y = py - 1; y = y < 0 ? 0 : (y > 127 ? 127 : y);
  int x = px - 1; x = x < 0 ? 0 : (x > 127 ? 127 : x);
  int src = (c << 14) + (y << 7) + x;
  apt[t] = a[src];
  bpt[t] = b[src];
}

// ---------------- init: random shifts + their costs (full-wave) -----------------
__global__ __launch_bounds__(256) void init_kernel(
    const float* __restrict__ apt, const float* __restrict__ bpt,
    uint32_t* __restrict__ npack, float* __restrict__ ncost, uint4 IK) {
  int t = (int)(blockIdx.x * blockDim.x + threadIdx.x);  // 8*16384
  int pix = t & (NPIX - 1);
  int s = t >> 14;
  int py0 = pix >> 7, px0 = pix & 127;
  uint32_t j0 = (uint32_t)(s * 2) * 16384u + (uint32_t)pix;
  int sy = rnd_int(IK, j0, 128u, 0u, 0);
  int sx = rnd_int(IK, j0 + 16384u, 128u, 0u, 0);
  float cst = cost_eval_pl(apt, bpt, py0, px0, sy, sx);
  npack[t] = (uint32_t)((sy << 7) | sx);
  ncost[t] = cst;
}

// ---------------- one PatchMatch iteration --------------------------------------
// b staged via global_load_lds into a SINGLE 9216 B buffer (10.4 KB total LDS ->
// ~15 blocks/CU). Per-phase order makes buffer reuse race-free AND latency-
// hidden: vmcnt(0) [loads landed] -> ds_read bv/av -> lgkmcnt(0) [reads in
// VGPRs, buffer dead] -> issue next phase's gl_lds (UNIFORM control flow --
// divergent masking of gl_lds waterfalls through scratch, R17 post-mortem) ->
// eval (~800 cy) overlaps their latency.
__global__ __launch_bounds__(64, 4) void step_kernel(
    const float* __restrict__ apt, const float* __restrict__ bpt,
    const uint32_t* __restrict__ ppack, const float* __restrict__ pcost,
    uint32_t* __restrict__ npack, float* __restrict__ ncost,
    uint4 K0, uint4 K1, uint4 K2, uint4 K3) {
  __shared__ f32x4 ldsb[576];          // 9216 B single buffer for b
  __shared__ f32x4 ldsa[72];           // 1152 B a-patch (8 phases x 9 positions)
  int bidx = (int)blockIdx.x;
  int pix = ((bidx & 7) << 11) | (bidx >> 3);   // XCD-contiguous remap (16384 = 8*2048)
  int lane = (int)threadIdx.x;
  int py0 = pix >> 7, px0 = pix & 127;
  int g = lane >> 3, s = lane & 7;

  uint32_t old_pack = 0u; float old_cost_f = 0.f;
  if (lane < 8) {
    old_pack = ppack[lane * NPIX + pix];
    old_cost_f = pcost[lane * NPIX + pix];
  }

  // candidate generation; order matches all_s = [old8, left8, right8, up8, down8, r0..r3]
  int sy, sx;
  if (g < 4) {
    int nh = py0, nw = px0, dsy = 0, dsx = 0;
    if (g == 0)      { nw = (px0 + 127) & 127; dsx = 1;  }
    else if (g == 1) { nw = (px0 + 1) & 127;   dsx = -1; }
    else if (g == 2) { nh = (py0 + 127) & 127; dsy = 1;  }
    else             { nh = (py0 + 1) & 127;   dsy = -1; }
    uint32_t p = ppack[s * NPIX + (nh << 7) + nw];
    sy = (int)(p >> 7) + dsy;
    sx = (int)(p & 127u) + dsx;
  } else {
    uint32_t p = ppack[s * NPIX + pix];
    uint4 Ki      = (g == 4) ? K0   : (g == 5) ? K1  : (g == 6) ? K2 : K3;
    uint32_t span = (g == 4) ? 129u : (g == 5) ? 33u : (g == 6) ? 9u : 3u;
    uint32_t mult = (g == 4) ? 16u  : (g == 5) ? 4u  : (g == 6) ? 4u : 1u;
    int minv      = (g == 4) ? -64  : (g == 5) ? -16 : (g == 6) ? -4 : -1;
    uint32_t j0 = (uint32_t)(s * 2) * 16384u + (uint32_t)pix;
    sy = (int)(p >> 7)   + rnd_int(Ki, j0, span, mult, minv);
    sx = (int)(p & 127u) + rnd_int(Ki, j0 + 16384u, span, mult, minv);
  }
  sy = sy < 0 ? 0 : (sy > 127 ? 127 : sy);
  sx = sx < 0 ? 0 : (sx > 127 ? 127 : sx);
  uint32_t cnd_pack = (uint32_t)((sy << 7) | sx);

  // ---- staging descriptors (phase-independent): lane stages 16B quad
  // f = i*64+lane of flat (candidate c = f/9, position p = f%9); computed once.
  int base_[9];
#pragma unroll
  for (int i = 0; i < 9; ++i) {
    int f = i * 64 + lane;
    int c = f / 9, p = f - c * 9;
    int dy = p / 3, dx = p - dy * 3;
    uint32_t pk = (uint32_t)__shfl((int)cnd_pack, c);
    int py = (int)(pk >> 7) + dy;
    int px = (int)(pk & 127u) + dx;
    base_[i] = (py * PW + px) * 4;
  }

  // ---- prologue: a-patch (72 quads) + b phase 0 via global_load_lds -----------
  {
    int q = lane;
    int ph = q / 9, pos = q - ph * 9;
    int dy = pos / 3, dx = pos - dy * 3;
    const float* gp = apt + (size_t)ph * (NPPAD * 4)
                     + (size_t)((py0 + dy) * PW + (px0 + dx)) * 4;
    __builtin_amdgcn_global_load_lds((glob_u32_t*)gp, (lds_u32_t*)&ldsa[0], 16, 0, 0);
  }
  if (lane < 8) {
    int q = 64 + lane;
    int ph = q / 9, pos = q - ph * 9;
    int dy = pos / 3, dx = pos - dy * 3;
    const float* gp = apt + (size_t)ph * (NPPAD * 4)
                     + (size_t)((py0 + dy) * PW + (px0 + dx)) * 4;
    __builtin_amdgcn_global_load_lds((glob_u32_t*)gp, (lds_u32_t*)&ldsa[64], 16, 0, 0);
  }

#define GLB(PH)                                                             \
  _Pragma("unroll")                                                         \
  for (int i = 0; i < 9; ++i) {                                             \
    __builtin_amdgcn_global_load_lds(                                       \
        (glob_u32_t*)(bpt + (size_t)(PH) * (NPPAD * 4) + base_[i]),         \
        (lds_u32_t*)&ldsb[i * 64], 16, 0, 0);                               \
  }

  GLB(0)

  // ---- 8 phases; accumulation ch = ph*4+j ascending, positions inner ->
  // bit-identical to reference.
  float acc = 0.f;

#define PHASE(PH, DOGL)                                                     \
  asm volatile("s_waitcnt vmcnt(0)" ::: "memory");                          \
  {                                                                         \
    f32x4 av[9], bv[9];                                                     \
    _Pragma("unroll")                                                       \
    for (int p = 0; p < 9; ++p) {                                           \
      bv[p] = ldsb[lane * 9 + p];                                           \
      av[p] = ldsa[(PH) * 9 + p];                                           \
    }                                                                       \
    asm volatile("s_waitcnt lgkmcnt(0)" ::: "memory");                      \
    DOGL                                                                    \
    _Pragma("unroll")                                                       \
    for (int j = 0; j < 4; ++j) {                                           \
      _Pragma("unroll")                                                     \
      for (int p = 0; p < 9; ++p) {                                         \
        float d = __fsub_rn(av[p][j], bv[p][j]);                            \
        acc = __fadd_rn(acc, __fmul_rn(d, d));                              \
      }                                                                     \
    }                                                                       \
  }

  PHASE(0, GLB(1))
  PHASE(1, GLB(2))
  PHASE(2, GLB(3))
  PHASE(3, GLB(4))
  PHASE(4, GLB(5))
  PHASE(5, GLB(6))
  PHASE(6, GLB(7))
  PHASE(7, )
#undef PHASE
#undef GLB

  float cnd_cost = acc;

  // stable top-8 (ascending cost, ties -> lower candidate idx), matching
  // lax.top_k. SELECT and EXTRACT fused per round to minimize live registers.
  unsigned long long new_key =
      ((unsigned long long)__float_as_uint(cnd_cost) << 32) | (unsigned)(8 + lane);
  unsigned long long old_key = (lane < 8)
      ? (((unsigned long long)__float_as_uint(old_cost_f) << 32) | (unsigned)lane)
      : ~0ull;
  bool new_used = false, old_used = (lane >= 8);

  uint32_t out_pack = 0u; float out_cost = 0.f;
#define TOPK_ROUND(R)                                                      \
  {                                                                        \
    unsigned long long kmin = new_used ? ~0ull : new_key;                  \
    if (!old_used && old_key < kmin) kmin = old_key;                       \
    _Pragma("unroll")                                                      \
    for (int off = 32; off; off >>= 1) {                                   \
      unsigned long long o = __shfl_xor(kmin, off);                        \
      if (o < kmin) kmin = o;                                              \
    }                                                                      \
    if (!new_used && new_key == kmin) new_used = true;                     \
    else if (!old_used && old_key == kmin) old_used = true;                \
    uint32_t idx = (uint32_t)kmin;                                         \
    float cst = __uint_as_float((uint32_t)(kmin >> 32));                   \
    int srcOld = (idx < 8u) ? (int)idx : 0;                                \
    int srcNew = (idx >= 8u) ? (int)(idx - 8u) : 0;                        \
    uint32_t po = __shfl(old_pack, srcOld);                                \
    uint32_t pn = __shfl(cnd_pack, srcNew);                                \
    uint32_t pk = (idx < 8u) ? po : pn;                                    \
    if (lane == R) { out_pack = pk; out_cost = cst; }                      \
  }
  TOPK_ROUND(0) TOPK_ROUND(1) TOPK_ROUND(2) TOPK_ROUND(3)
  TOPK_ROUND(4) TOPK_ROUND(5) TOPK_ROUND(6) TOPK_ROUND(7)
#undef TOPK_ROUND

  if (lane < 8) {
    npack[lane * NPIX + pix] = out_pack;
    ncost[lane * NPIX + pix] = out_cost;
  }
}

// ---------------- softmax weights over 8 costs ----------------------------------
__global__ __launch_bounds__(256) void weights_kernel(
    const float* __restrict__ cost0, float* __restrict__ wbuf) {
  int pix = (int)(blockIdx.x * blockDim.x + threadIdx.x);
  if (pix >= NPIX) return;
  float c[KNN];
  float m = 3.4e38f;
#pragma unroll
  for (int s = 0; s < KNN; ++s) { c[s] = cost0[s * NPIX + pix]; m = fminf(m, c[s]); }
  float e[KNN]; float sum = 0.f;
#pragma unroll
  for (int s = 0; s < KNN; ++s) { e[s] = expf(m - c[s]); sum += e[s]; }
  float inv = 1.f / sum;
#pragma unroll
  for (int s = 0; s < KNN; ++s) wbuf[s * NPIX + pix] = e[s] * inv;
}

// ---------------- weighted gather of v ------------------------------------------
__global__ __launch_bounds__(256) void out_kernel(
    const float* __restrict__ v, const uint32_t* __restrict__ pack0,
    const float* __restrict__ wbuf, float* __restrict__ out) {
  int t = (int)(blockIdx.x * blockDim.x + threadIdx.x);  // 4*64*128*128 threads
  int pix = t & (NPIX - 1);
  int ch = t >> 14;  // n*64 + c2
  const float* vc = v + ((size_t)ch << 14);
  float acc = 0.f;
#pragma unroll
  for (int s = 0; s < KNN; ++s) {
    uint32_t p = pack0[s * NPIX + pix];   // p == sy*128+sx
    float wgt = wbuf[s * NPIX + pix];
    acc = fmaf(wgt, vc[p], acc);
  }
  out[t] = acc;
}

// ---------------- host helpers ---------------------------------------------------
// foldlike split (jax_threefry_partitionable=True): key_i = TF(key, (0, i))
static void h_split_fl(uint32_t ka, uint32_t kb, uint32_t o[4]) {
  tf2x32(ka, kb, 0u, 0u, o[0], o[1]);  // keys[0]
  tf2x32(ka, kb, 0u, 1u, o[2], o[3]);  // keys[1]
}

extern "C" void kernel_launch(void* const* d_in, const int* in_sizes, int n_in,
                              void* d_out, int out_size, void* d_ws, size_t ws_size,
                              hipStream_t stream) {
  const float* q = (const float*)d_in[0];  // (1,32,128,128)
  const float* k = (const float*)d_in[1];  // (1,32,128,128)
  const float* v = (const float*)d_in[2];  // (4,64,128,128)
  float* out = (float*)d_out;

  uint32_t* ws = (uint32_t*)d_ws;
  uint32_t* pk[2] = { ws, ws + (size_t)KNN * NPIX };
  float* ct[2] = { (float*)(ws + (size_t)2 * KNN * NPIX),
                   (float*)(ws + (size_t)3 * KNN * NPIX) };
  float* wbuf = (float*)(ws + (size_t)4 * KNN * NPIX);
  float* apt  = (float*)(ws + (size_t)5 * KNN * NPIX);
  float* bpt  = apt + (size_t)32 * NPPAD;

  // key chain on host (pure arithmetic; graph-capture safe, deterministic)
  uint32_t sp[4];
  h_split_fl(0u, 42u, sp);                      // split(key(42)) [foldlike]
  uint32_t k0a = sp[0], k0b = sp[1];            // k0  (initial randint key)
  uint32_t kMa = sp[2], kMb = sp[3];            // key (closed over by scan body)

  pad_kernel<<<(32 * NPPAD + 255) / 256, 256, 0, stream>>>(q, k, apt, bpt);

  uint32_t ik[4];
  h_split_fl(k0a, k0b, ik);                     // randint's internal split of k0
  init_kernel<<<(KNN * NPIX) / 256, 256, 0, stream>>>(apt, bpt, pk[0], ct[0],
                                        make_uint4(ik[0], ik[1], ik[2], ik[3]));

  for (int it = 0; it < 10; ++it) {
    uint32_t ka, kb;
    tf2x32(kMa, kMb, 0u, (uint32_t)it, ka, kb); // kk = fold_in(key, it)
    uint4 K[4];
    for (int i = 0; i < 4; ++i) {
      uint32_t ia, ib;
      tf2x32(ka, kb, 0u, (uint32_t)i, ia, ib);  // ki = fold_in(kk, i)
      uint32_t o[4];
      h_split_fl(ia, ib, o);                    // randint's internal split of ki
      K[i] = make_uint4(o[0], o[1], o[2], o[3]);
    }
    step_kernel<<<NPIX, 64, 0, stream>>>(apt, bpt, pk[it & 1], ct[it & 1],
                                         pk[(it + 1) & 1], ct[(it + 1) & 1],
                                         K[0], K[1], K[2], K[3]);
  }

  weights_kernel<<<NPIX / 256, 256, 0, stream>>>(ct[0], wbuf);
  out_kernel<<<(4 * 64 * NPIX) / 256, 256, 0, stream>>>(v, pk[0], wbuf, out);
}

// Round 19
// 891.712 us; speedup vs baseline: 12.0727x; 1.0153x over previous
//
#include <hip/hip_runtime.h>
#include <cstdint>

#define NPIX 16384
#define KNN 8
#define PW 130                 // padded width/height
#define NPPAD (PW * PW)        // padded positions: 16900
#define NPH 8                  // phases (4 channels each)

typedef float f32x4 __attribute__((ext_vector_type(4)));
typedef __attribute__((address_space(3))) uint32_t lds_u32_t;
typedef const __attribute__((address_space(1))) uint32_t glob_u32_t;

// ---------------- Threefry-2x32 (exact JAX semantics: 20 rounds) ----------------
__host__ __device__ __forceinline__ void tf2x32(uint32_t k0, uint32_t k1,
                                                uint32_t x0, uint32_t x1,
                                                uint32_t& o0, uint32_t& o1) {
  uint32_t ks2 = k0 ^ k1 ^ 0x1BD11BDAu;
  x0 += k0; x1 += k1;
#define TFR(r) { x0 += x1; x1 = (x1 << r) | (x1 >> (32 - r)); x1 ^= x0; }
  TFR(13) TFR(15) TFR(26) TFR(6)  x0 += k1;  x1 += ks2 + 1u;
  TFR(17) TFR(29) TFR(16) TFR(24) x0 += ks2; x1 += k0 + 2u;
  TFR(13) TFR(15) TFR(26) TFR(6)  x0 += k0;  x1 += k1 + 3u;
  TFR(17) TFR(29) TFR(16) TFR(24) x0 += k1;  x1 += ks2 + 4u;
  TFR(13) TFR(15) TFR(26) TFR(6)  x0 += ks2; x1 += k0 + 5u;
#undef TFR
  o0 = x0; o1 = x1;
}

// partitionable-threefry random_bits (32-bit): element j -> w0^w1 of TF(key,(0,j))
__device__ __forceinline__ uint32_t rbits32(uint32_t ka, uint32_t kb, uint32_t j) {
  uint32_t o0, o1;
  tf2x32(ka, kb, 0u, j, o0, o1);
  return o0 ^ o1;
}

// randint element draw; K = (k1a,k1b,k2a,k2b) = foldlike-split of randint key
__device__ __forceinline__ int rnd_int(uint4 K, uint32_t j, uint32_t span,
                                       uint32_t mult, int minv) {
  uint32_t hi = rbits32(K.x, K.y, j);
  uint32_t lo = rbits32(K.z, K.w, j);
  uint32_t off = ((hi % span) * mult + (lo % span)) % span;
  return minv + (int)off;
}

// ---------------- pad + transpose a,b to [8][130][130][4] -----------------------
__global__ __launch_bounds__(256) void pad_kernel(
    const float* __restrict__ a, const float* __restrict__ b,
    float* __restrict__ apt, float* __restrict__ bpt) {
  int t = (int)(blockIdx.x * blockDim.x + threadIdx.x);
  if (t >= 32 * NPPAD) return;
  int lo = t & 3;
  int rest = t >> 2;
  int pos = rest % NPPAD;
  int ph = rest / NPPAD;
  int c = ph * 4 + lo;
  int py = pos / PW, px = pos % PW;
  int y = py - 1; y = y < 0 ? 0 : (y > 127 ? 127 : y);
  int x = px - 1; x = x < 0 ? 0 : (x > 127 ? 127 : x);
  int src = (c << 14) + (y << 7) + x;
  apt[t] = a[src];
  bpt[t] = b[src];
}

// ---------------- transpose v to channel-last vtr[pix][256] ---------------------
// Reads coalesced; scattered 4B stores (fire-and-forget, no latency stall).
__global__ __launch_bounds__(256) void vtr_kernel(
    const float* __restrict__ v, float* __restrict__ vtr) {
  int t = (int)(blockIdx.x * blockDim.x + threadIdx.x);  // 4*64*16384
  int ch = t >> 14, pix = t & (NPIX - 1);
  vtr[(size_t)pix * 256 + ch] = v[t];
}

// ---------------- init: staged like step (wave = 8 pixels x 8 seeds) ------------
// b staged via global_load_lds single 9216B buffer; a per-lane (8 consecutive
// pixels share lines). RNG element j0 = s*2*16384+pix and the (ch,dy,dx)
// accumulation chain identical to the per-lane version -> bit-exact.
__global__ __launch_bounds__(64, 4) void init_kernel(
    const float* __restrict__ apt, const float* __restrict__ bpt,
    uint32_t* __restrict__ npack, float* __restrict__ ncost, uint4 IK) {
  __shared__ f32x4 ldsb[576];
  int bidx = (int)blockIdx.x;                   // 2048 blocks
  int gid = (bidx & 7) * 256 + (bidx >> 3);     // XCD-contiguous remap
  int lane = (int)threadIdx.x;
  int s = lane >> 3, pp = lane & 7;
  int pix = gid * 8 + pp;                       // 8 consecutive pixels, same row
  int py0 = pix >> 7, px0 = pix & 127;
  uint32_t j0 = (uint32_t)(s * 2) * 16384u + (uint32_t)pix;
  int sy = rnd_int(IK, j0, 128u, 0u, 0);
  int sx = rnd_int(IK, j0 + 16384u, 128u, 0u, 0);
  uint32_t cnd_pack = (uint32_t)((sy << 7) | sx);

  int base_[9];
#pragma unroll
  for (int i = 0; i < 9; ++i) {
    int f = i * 64 + lane;
    int c = f / 9, p = f - c * 9;
    int dy = p / 3, dx = p - dy * 3;
    uint32_t pk = (uint32_t)__shfl((int)cnd_pack, c);
    int py = (int)(pk >> 7) + dy;
    int px = (int)(pk & 127u) + dx;
    base_[i] = (py * PW + px) * 4;
  }

#define GLBI(PH)                                                            \
  _Pragma("unroll")                                                         \
  for (int i = 0; i < 9; ++i) {                                             \
    __builtin_amdgcn_global_load_lds(                                       \
        (glob_u32_t*)(bpt + (size_t)(PH) * (NPPAD * 4) + base_[i]),         \
        (lds_u32_t*)&ldsb[i * 64], 16, 0, 0);                               \
  }

  GLBI(0)

  float acc = 0.f;
#define IPHASE(PH, DOGL)                                                    \
  asm volatile("s_waitcnt vmcnt(0)" ::: "memory");                          \
  {                                                                         \
    f32x4 av[9], bv[9];                                                     \
    _Pragma("unroll")                                                       \
    for (int p = 0; p < 9; ++p) {                                           \
      int dy = p / 3, dx = p - dy * 3;                                      \
      bv[p] = ldsb[lane * 9 + p];                                           \
      av[p] = *(const f32x4*)(apt + (size_t)(PH) * (NPPAD * 4)              \
              + (size_t)((py0 + dy) * PW + (px0 + dx)) * 4);                \
    }                                                                       \
    asm volatile("s_waitcnt lgkmcnt(0)" ::: "memory");                      \
    DOGL                                                                    \
    _Pragma("unroll")                                                       \
    for (int j = 0; j < 4; ++j) {                                           \
      _Pragma("unroll")                                                     \
      for (int p = 0; p < 9; ++p) {                                         \
        float d = __fsub_rn(av[p][j], bv[p][j]);                            \
        acc = __fadd_rn(acc, __fmul_rn(d, d));                              \
      }                                                                     \
    }                                                                       \
  }

  IPHASE(0, GLBI(1))
  IPHASE(1, GLBI(2))
  IPHASE(2, GLBI(3))
  IPHASE(3, GLBI(4))
  IPHASE(4, GLBI(5))
  IPHASE(5, GLBI(6))
  IPHASE(6, GLBI(7))
  IPHASE(7, )
#undef IPHASE
#undef GLBI

  npack[s * NPIX + pix] = cnd_pack;
  ncost[s * NPIX + pix] = acc;
}

// ---------------- one PatchMatch iteration (R14/R18 verified optimum) -----------
__global__ __launch_bounds__(64, 4) void step_kernel(
    const float* __restrict__ apt, const float* __restrict__ bpt,
    const uint32_t* __restrict__ ppack, const float* __restrict__ pcost,
    uint32_t* __restrict__ npack, float* __restrict__ ncost,
    uint4 K0, uint4 K1, uint4 K2, uint4 K3) {
  __shared__ f32x4 ldsb[576];          // 9216 B single buffer for b
  __shared__ f32x4 ldsa[72];           // 1152 B a-patch (8 phases x 9 positions)
  int bidx = (int)blockIdx.x;
  int pix = ((bidx & 7) << 11) | (bidx >> 3);   // XCD-contiguous remap
  int lane = (int)threadIdx.x;
  int py0 = pix >> 7, px0 = pix & 127;
  int g = lane >> 3, s = lane & 7;

  uint32_t old_pack = 0u; float old_cost_f = 0.f;
  if (lane < 8) {
    old_pack = ppack[lane * NPIX + pix];
    old_cost_f = pcost[lane * NPIX + pix];
  }

  // candidate generation; order matches all_s = [old8, left8, right8, up8, down8, r0..r3]
  int sy, sx;
  if (g < 4) {
    int nh = py0, nw = px0, dsy = 0, dsx = 0;
    if (g == 0)      { nw = (px0 + 127) & 127; dsx = 1;  }
    else if (g == 1) { nw = (px0 + 1) & 127;   dsx = -1; }
    else if (g == 2) { nh = (py0 + 127) & 127; dsy = 1;  }
    else             { nh = (py0 + 1) & 127;   dsy = -1; }
    uint32_t p = ppack[s * NPIX + (nh << 7) + nw];
    sy = (int)(p >> 7) + dsy;
    sx = (int)(p & 127u) + dsx;
  } else {
    uint32_t p = ppack[s * NPIX + pix];
    uint4 Ki      = (g == 4) ? K0   : (g == 5) ? K1  : (g == 6) ? K2 : K3;
    uint32_t span = (g == 4) ? 129u : (g == 5) ? 33u : (g == 6) ? 9u : 3u;
    uint32_t mult = (g == 4) ? 16u  : (g == 5) ? 4u  : (g == 6) ? 4u : 1u;
    int minv      = (g == 4) ? -64  : (g == 5) ? -16 : (g == 6) ? -4 : -1;
    uint32_t j0 = (uint32_t)(s * 2) * 16384u + (uint32_t)pix;
    sy = (int)(p >> 7)   + rnd_int(Ki, j0, span, mult, minv);
    sx = (int)(p & 127u) + rnd_int(Ki, j0 + 16384u, span, mult, minv);
  }
  sy = sy < 0 ? 0 : (sy > 127 ? 127 : sy);
  sx = sx < 0 ? 0 : (sx > 127 ? 127 : sx);
  uint32_t cnd_pack = (uint32_t)((sy << 7) | sx);

  int base_[9];
#pragma unroll
  for (int i = 0; i < 9; ++i) {
    int f = i * 64 + lane;
    int c = f / 9, p = f - c * 9;
    int dy = p / 3, dx = p - dy * 3;
    uint32_t pk = (uint32_t)__shfl((int)cnd_pack, c);
    int py = (int)(pk >> 7) + dy;
    int px = (int)(pk & 127u) + dx;
    base_[i] = (py * PW + px) * 4;
  }

  // prologue: a-patch (72 quads) + b phase 0 via global_load_lds
  {
    int q = lane;
    int ph = q / 9, pos = q - ph * 9;
    int dy = pos / 3, dx = pos - dy * 3;
    const float* gp = apt + (size_t)ph * (NPPAD * 4)
                     + (size_t)((py0 + dy) * PW + (px0 + dx)) * 4;
    __builtin_amdgcn_global_load_lds((glob_u32_t*)gp, (lds_u32_t*)&ldsa[0], 16, 0, 0);
  }
  if (lane < 8) {
    int q = 64 + lane;
    int ph = q / 9, pos = q - ph * 9;
    int dy = pos / 3, dx = pos - dy * 3;
    const float* gp = apt + (size_t)ph * (NPPAD * 4)
                     + (size_t)((py0 + dy) * PW + (px0 + dx)) * 4;
    __builtin_amdgcn_global_load_lds((glob_u32_t*)gp, (lds_u32_t*)&ldsa[64], 16, 0, 0);
  }

#define GLB(PH)                                                             \
  _Pragma("unroll")                                                         \
  for (int i = 0; i < 9; ++i) {                                             \
    __builtin_amdgcn_global_load_lds(                                       \
        (glob_u32_t*)(bpt + (size_t)(PH) * (NPPAD * 4) + base_[i]),         \
        (lds_u32_t*)&ldsb[i * 64], 16, 0, 0);                               \
  }

  GLB(0)

  float acc = 0.f;
#define PHASE(PH, DOGL)                                                     \
  asm volatile("s_waitcnt vmcnt(0)" ::: "memory");                          \
  {                                                                         \
    f32x4 av[9], bv[9];                                                     \
    _Pragma("unroll")                                                       \
    for (int p = 0; p < 9; ++p) {                                           \
      bv[p] = ldsb[lane * 9 + p];                                           \
      av[p] = ldsa[(PH) * 9 + p];                                           \
    }                                                                       \
    asm volatile("s_waitcnt lgkmcnt(0)" ::: "memory");                      \
    DOGL                                                                    \
    _Pragma("unroll")                                                       \
    for (int j = 0; j < 4; ++j) {                                           \
      _Pragma("unroll")                                                     \
      for (int p = 0; p < 9; ++p) {                                         \
        float d = __fsub_rn(av[p][j], bv[p][j]);                            \
        acc = __fadd_rn(acc, __fmul_rn(d, d));                              \
      }                                                                     \
    }                                                                       \
  }

  PHASE(0, GLB(1))
  PHASE(1, GLB(2))
  PHASE(2, GLB(3))
  PHASE(3, GLB(4))
  PHASE(4, GLB(5))
  PHASE(5, GLB(6))
  PHASE(6, GLB(7))
  PHASE(7, )
#undef PHASE
#undef GLB

  float cnd_cost = acc;

  unsigned long long new_key =
      ((unsigned long long)__float_as_uint(cnd_cost) << 32) | (unsigned)(8 + lane);
  unsigned long long old_key = (lane < 8)
      ? (((unsigned long long)__float_as_uint(old_cost_f) << 32) | (unsigned)lane)
      : ~0ull;
  bool new_used = false, old_used = (lane >= 8);

  uint32_t out_pack = 0u; float out_cost = 0.f;
#define TOPK_ROUND(R)                                                      \
  {                                                                        \
    unsigned long long kmin = new_used ? ~0ull : new_key;                  \
    if (!old_used && old_key < kmin) kmin = old_key;                       \
    _Pragma("unroll")                                                      \
    for (int off = 32; off; off >>= 1) {                                   \
      unsigned long long o = __shfl_xor(kmin, off);                        \
      if (o < kmin) kmin = o;                                              \
    }                                                                      \
    if (!new_used && new_key == kmin) new_used = true;                     \
    else if (!old_used && old_key == kmin) old_used = true;                \
    uint32_t idx = (uint32_t)kmin;                                         \
    float cst = __uint_as_float((uint32_t)(kmin >> 32));                   \
    int srcOld = (idx < 8u) ? (int)idx : 0;                                \
    int srcNew = (idx >= 8u) ? (int)(idx - 8u) : 0;                        \
    uint32_t po = __shfl(old_pack, srcOld);                                \
    uint32_t pn = __shfl(cnd_pack, srcNew);                                \
    uint32_t pk = (idx < 8u) ? po : pn;                                    \
    if (lane == R) { out_pack = pk; out_cost = cst; }                      \
  }
  TOPK_ROUND(0) TOPK_ROUND(1) TOPK_ROUND(2) TOPK_ROUND(3)
  TOPK_ROUND(4) TOPK_ROUND(5) TOPK_ROUND(6) TOPK_ROUND(7)
#undef TOPK_ROUND

  if (lane < 8) {
    npack[lane * NPIX + pix] = out_pack;
    ncost[lane * NPIX + pix] = out_cost;
  }
}

// ---------------- fused softmax + weighted gather (channel-last v) --------------
// One wave per pixel: 8 coalesced f32x4 row-gathers per lane from vtr[p][256];
// accumulation order s ascending (matches reference sum); scattered 4B out
// stores (fire-and-forget).
__global__ __launch_bounds__(64) void outfused_kernel(
    const float* __restrict__ vtr, const uint32_t* __restrict__ pack0,
    const float* __restrict__ cost0, float* __restrict__ out) {
  int bidx = (int)blockIdx.x;
  int pix = ((bidx & 7) << 11) | (bidx >> 3);
  int lane = (int)threadIdx.x;
  float cv = 0.f; uint32_t pv = 0u;
  if (lane < 8) {
    cv = cost0[lane * NPIX + pix];
    pv = pack0[lane * NPIX + pix];
  }
  float c[KNN]; uint32_t p[KNN];
#pragma unroll
  for (int s = 0; s < KNN; ++s) {
    c[s] = __shfl(cv, s);
    p[s] = (uint32_t)__shfl((int)pv, s);
  }
  float m = c[0];
#pragma unroll
  for (int s = 1; s < KNN; ++s) m = fminf(m, c[s]);
  float e[KNN]; float sum = 0.f;
#pragma unroll
  for (int s = 0; s < KNN; ++s) { e[s] = expf(m - c[s]); sum += e[s]; }
  float inv = 1.f / sum;
  f32x4 acc = {0.f, 0.f, 0.f, 0.f};
#pragma unroll
  for (int s = 0; s < KNN; ++s) {
    f32x4 r = *(const f32x4*)(vtr + (size_t)p[s] * 256 + lane * 4);
    float w = e[s] * inv;
#pragma unroll
    for (int j = 0; j < 4; ++j) acc[j] = fmaf(w, r[j], acc[j]);
  }
#pragma unroll
  for (int j = 0; j < 4; ++j)
    out[(size_t)(lane * 4 + j) * NPIX + pix] = acc[j];
}

// ---------------- fallback path (R18): weights + gather from original v --------
__global__ __launch_bounds__(256) void weights_kernel(
    const float* __restrict__ cost0, float* __restrict__ wbuf) {
  int pix = (int)(blockIdx.x * blockDim.x + threadIdx.x);
  if (pix >= NPIX) return;
  float c[KNN];
  float m = 3.4e38f;
#pragma unroll
  for (int s = 0; s < KNN; ++s) { c[s] = cost0[s * NPIX + pix]; m = fminf(m, c[s]); }
  float e[KNN]; float sum = 0.f;
#pragma unroll
  for (int s = 0; s < KNN; ++s) { e[s] = expf(m - c[s]); sum += e[s]; }
  float inv = 1.f / sum;
#pragma unroll
  for (int s = 0; s < KNN; ++s) wbuf[s * NPIX + pix] = e[s] * inv;
}

__global__ __launch_bounds__(256) void out_kernel(
    const float* __restrict__ v, const uint32_t* __restrict__ pack0,
    const float* __restrict__ wbuf, float* __restrict__ out) {
  int t = (int)(blockIdx.x * blockDim.x + threadIdx.x);
  int pix = t & (NPIX - 1);
  int ch = t >> 14;
  const float* vc = v + ((size_t)ch << 14);
  float acc = 0.f;
#pragma unroll
  for (int s = 0; s < KNN; ++s) {
    uint32_t p = pack0[s * NPIX + pix];
    float wgt = wbuf[s * NPIX + pix];
    acc = fmaf(wgt, vc[p], acc);
  }
  out[t] = acc;
}

// ---------------- host helpers ---------------------------------------------------
// foldlike split (jax_threefry_partitionable=True): key_i = TF(key, (0, i))
static void h_split_fl(uint32_t ka, uint32_t kb, uint32_t o[4]) {
  tf2x32(ka, kb, 0u, 0u, o[0], o[1]);  // keys[0]
  tf2x32(ka, kb, 0u, 1u, o[2], o[3]);  // keys[1]
}

extern "C" void kernel_launch(void* const* d_in, const int* in_sizes, int n_in,
                              void* d_out, int out_size, void* d_ws, size_t ws_size,
                              hipStream_t stream) {
  const float* q = (const float*)d_in[0];  // (1,32,128,128)
  const float* k = (const float*)d_in[1];  // (1,32,128,128)
  const float* v = (const float*)d_in[2];  // (4,64,128,128)
  float* out = (float*)d_out;

  uint32_t* ws = (uint32_t*)d_ws;
  uint32_t* pk[2] = { ws, ws + (size_t)KNN * NPIX };
  float* ct[2] = { (float*)(ws + (size_t)2 * KNN * NPIX),
                   (float*)(ws + (size_t)3 * KNN * NPIX) };
  float* wbuf = (float*)(ws + (size_t)4 * KNN * NPIX);
  float* apt  = (float*)(ws + (size_t)5 * KNN * NPIX);
  float* bpt  = apt + (size_t)32 * NPPAD;
  float* vtr  = bpt + (size_t)32 * NPPAD;
  size_t need = ((size_t)5 * KNN * NPIX + (size_t)64 * NPPAD
                 + (size_t)4 * 64 * NPIX) * 4u;
  bool use_vtr = (ws_size >= need);

  // key chain on host (pure arithmetic; graph-capture safe, deterministic)
  uint32_t sp[4];
  h_split_fl(0u, 42u, sp);                      // split(key(42)) [foldlike]
  uint32_t k0a = sp[0], k0b = sp[1];            // k0  (initial randint key)
  uint32_t kMa = sp[2], kMb = sp[3];            // key (closed over by scan body)

  pad_kernel<<<(32 * NPPAD + 255) / 256, 256, 0, stream>>>(q, k, apt, bpt);
  if (use_vtr)
    vtr_kernel<<<(4 * 64 * NPIX) / 256, 256, 0, stream>>>(v, vtr);

  uint32_t ik[4];
  h_split_fl(k0a, k0b, ik);                     // randint's internal split of k0
  init_kernel<<<NPIX / 8, 64, 0, stream>>>(apt, bpt, pk[0], ct[0],
                                        make_uint4(ik[0], ik[1], ik[2], ik[3]));

  for (int it = 0; it < 10; ++it) {
    uint32_t ka, kb;
    tf2x32(kMa, kMb, 0u, (uint32_t)it, ka, kb); // kk = fold_in(key, it)
    uint4 K[4];
    for (int i = 0; i < 4; ++i) {
      uint32_t ia, ib;
      tf2x32(ka, kb, 0u, (uint32_t)i, ia, ib);  // ki = fold_in(kk, i)
      uint32_t o[4];
      h_split_fl(ia, ib, o);                    // randint's internal split of ki
      K[i] = make_uint4(o[0], o[1], o[2], o[3]);
    }
    step_kernel<<<NPIX, 64, 0, stream>>>(apt, bpt, pk[it & 1], ct[it & 1],
                                         pk[(it + 1) & 1], ct[(it + 1) & 1],
                                         K[0], K[1], K[2], K[3]);
  }

  if (use_vtr) {
    outfused_kernel<<<NPIX, 64, 0, stream>>>(vtr, pk[0], ct[0], out);
  } else {
    weights_kernel<<<NPIX / 256, 256, 0, stream>>>(ct[0], wbuf);
    out_kernel<<<(4 * 64 * NPIX) / 256, 256, 0, stream>>>(v, pk[0], wbuf, out);
  }
}